// Round 10
// baseline (85.059 us; speedup 1.0000x reference)
//
#include <hip/hip_runtime.h>
#include <hip/hip_bf16.h>

typedef float f32x4 __attribute__((ext_vector_type(4)));
typedef __bf16 bf16x8 __attribute__((ext_vector_type(8)));
typedef __bf16 bf16x4 __attribute__((ext_vector_type(4)));

__device__ __forceinline__ void gload_lds16(const __bf16* g, __bf16* l) {
  __builtin_amdgcn_global_load_lds(
      (const __attribute__((address_space(1))) void*)g,
      (__attribute__((address_space(3))) void*)l, 16, 0, 0);
}

// ---------------------------------------------------------------------------
// convert: fp32 -> bf16 for x (2M elems) and Wq/Wk/Wv/Wo (1M each)
// ---------------------------------------------------------------------------
__global__ __launch_bounds__(256) void convert_all(
    const float* __restrict__ x, const float* __restrict__ wq,
    const float* __restrict__ wk, const float* __restrict__ wv,
    const float* __restrict__ wo, __bf16* __restrict__ dst)
{
  int t = blockIdx.x * 256 + threadIdx.x;
  const float* src; size_t soff;
  if (t < 262144) { src = x; soff = (size_t)t * 8; }
  else {
    int r = (t - 262144) >> 17;
    src = (r == 0) ? wq : (r == 1) ? wk : (r == 2) ? wv : wo;
    soff = (size_t)((t - 262144) & 131071) * 8;
  }
  float4 f0 = *(const float4*)(src + soff);
  float4 f1 = *(const float4*)(src + soff + 4);
  bf16x8 o;
  o[0]=(__bf16)f0.x; o[1]=(__bf16)f0.y; o[2]=(__bf16)f0.z; o[3]=(__bf16)f0.w;
  o[4]=(__bf16)f1.x; o[5]=(__bf16)f1.y; o[6]=(__bf16)f1.z; o[7]=(__bf16)f1.w;
  *(bf16x8*)(dst + (size_t)t * 8) = o;
}

// ---------------------------------------------------------------------------
// GEMM: C[m][n] = sum_k A[m][k] * B[n][k].  Templated tile BMxBN, BK=64.
// global_load_lds w=16, swizzle on the global source (rule #21).
// ---------------------------------------------------------------------------
template <int BM, int BN, typename OutT>
__global__ __launch_bounds__(256) void gemm_bt(
    const __bf16* __restrict__ A,
    const __bf16* __restrict__ B0, const __bf16* __restrict__ B1, const __bf16* __restrict__ B2,
    OutT* __restrict__ C0, OutT* __restrict__ C1, OutT* __restrict__ C2,
    int M, int N, int K)
{
  const __bf16* B = (blockIdx.z == 0) ? B0 : (blockIdx.z == 1) ? B1 : B2;
  OutT* C = (blockIdx.z == 0) ? C0 : (blockIdx.z == 1) ? C1 : C2;

  constexpr int BK = 64;
  constexpr int MT = BM / 32, NT = BN / 32;
  __shared__ __align__(16) __bf16 As[BM * BK];
  __shared__ __align__(16) __bf16 Bs[BN * BK];

  const int tid = threadIdx.x, w = tid >> 6, l = tid & 63;
  const int wr = w >> 1, wc = w & 1;
  const int g = l >> 4, c16 = l & 15;
  const int bm = blockIdx.y, bn = blockIdx.x;
  const int sr8 = l >> 3, sc = l & 7;

  f32x4 acc[MT][NT] = {};
  const int nk = K >> 6;

  for (int kt = 0; kt < nk; ++kt) {
    __syncthreads();
#pragma unroll
    for (int i = w; i < BM / 8; i += 4) {
      int row = i * 8 + sr8;
      int sch = sc ^ (row & 7);
      gload_lds16(A + (size_t)(bm * BM + row) * K + kt * 64 + sch * 8, As + i * 8 * 64);
    }
#pragma unroll
    for (int i = w; i < BN / 8; i += 4) {
      int row = i * 8 + sr8;
      int sch = sc ^ (row & 7);
      gload_lds16(B + (size_t)(bn * BN + row) * K + kt * 64 + sch * 8, Bs + i * 8 * 64);
    }
    __syncthreads();

    bf16x8 af[MT][2], bf[NT][2];
#pragma unroll
    for (int mt = 0; mt < MT; ++mt) {
      int row = wr * (BM / 2) + mt * 16 + c16;
#pragma unroll
      for (int kk = 0; kk < 2; ++kk)
        af[mt][kk] = *(const bf16x8*)(As + row * 64 + (((kk * 4 + g) ^ (row & 7)) * 8));
    }
#pragma unroll
    for (int nt = 0; nt < NT; ++nt) {
      int row = wc * (BN / 2) + nt * 16 + c16;
#pragma unroll
      for (int kk = 0; kk < 2; ++kk)
        bf[nt][kk] = *(const bf16x8*)(Bs + row * 64 + (((kk * 4 + g) ^ (row & 7)) * 8));
    }
#pragma unroll
    for (int kk = 0; kk < 2; ++kk)
#pragma unroll
      for (int mt = 0; mt < MT; ++mt)
#pragma unroll
        for (int nt = 0; nt < NT; ++nt)
          acc[mt][nt] = __builtin_amdgcn_mfma_f32_16x16x32_bf16(af[mt][kk], bf[nt][kk], acc[mt][nt], 0, 0, 0);
  }

#pragma unroll
  for (int mt = 0; mt < MT; ++mt)
#pragma unroll
    for (int nt = 0; nt < NT; ++nt)
#pragma unroll
      for (int r = 0; r < 4; ++r) {
        int row = bm * BM + wr * (BM / 2) + mt * 16 + g * 4 + r;
        int col = bn * BN + wc * (BN / 2) + nt * 16 + c16;
        C[(size_t)row * N + col] = (OutT)acc[mt][nt][r];
      }
}

// ---------------------------------------------------------------------------
// RoPE + justnorm + sqk scale. Q scaled by 8*log2(e) (SDPA scale + exp2 fold).
// ---------------------------------------------------------------------------
__global__ __launch_bounds__(256) void rope_norm(
    const __bf16* __restrict__ q, const __bf16* __restrict__ k,
    const float* __restrict__ sqk, __bf16* __restrict__ qo, __bf16* __restrict__ ko)
{
  int gt = blockIdx.x * 256 + threadIdx.x;
  int i = gt & 31;
  int row = gt >> 5;
  int h = row & 15;
  int n = row >> 4;

  float inv = exp2f(-(float)i * 0.415241011860919f);
  float ang = (float)n * inv;
  float s, c;
  sincosf(ang, &s, &c);

  const __bf16* qp = q + (size_t)row * 64;
  const __bf16* kp = k + (size_t)row * 64;
  float q1 = (float)qp[i], q2 = (float)qp[i + 32];
  float k1 = (float)kp[i], k2 = (float)kp[i + 32];
  float qa = q1 * c - q2 * s, qb2 = q1 * s + q2 * c;
  float ka = k1 * c - k2 * s, kb2 = k1 * s + k2 * c;

  float ssq = qa * qa + qb2 * qb2;
  float ssk = ka * ka + kb2 * kb2;
#pragma unroll
  for (int m2 = 1; m2 < 32; m2 <<= 1) {
    ssq += __shfl_xor(ssq, m2, 32);
    ssk += __shfl_xor(ssk, m2, 32);
  }
  float rq = rsqrtf(ssq), rk = rsqrtf(ssk);
  float s1 = sqk[h * 64 + i] * 32.0f;
  float s2 = sqk[h * 64 + i + 32] * 32.0f;
  const float QSC = 8.0f * 1.4426950408889634f;   // sqrt(64) * log2(e)

  qo[(size_t)row * 64 + i]      = (__bf16)(qa * rq * s1 * QSC);
  qo[(size_t)row * 64 + i + 32] = (__bf16)(qb2 * rq * s2 * QSC);
  ko[(size_t)row * 64 + i]      = (__bf16)(ka * rk * s1);
  ko[(size_t)row * 64 + i + 32] = (__bf16)(kb2 * rk * s2);
}

// ---------------------------------------------------------------------------
// V transpose: vt[h][d][n] = v[n][h*64+d]
// ---------------------------------------------------------------------------
__global__ __launch_bounds__(256) void vtrans(const __bf16* __restrict__ v, __bf16* __restrict__ vt)
{
  __shared__ __align__(16) __bf16 t[64 * 72];
  int h = blockIdx.y;
  int n0 = blockIdx.x * 64;
  int tid = threadIdx.x;
#pragma unroll
  for (int j = 0; j < 2; ++j) {
    int idx = tid + j * 256;
    int r = idx >> 3, c = (idx & 7) * 8;
    bf16x8 val = *(const bf16x8*)(v + (size_t)(n0 + r) * 1024 + h * 64 + c);
    *(bf16x8*)&t[r * 72 + c] = val;
  }
  __syncthreads();
#pragma unroll
  for (int j = 0; j < 2; ++j) {
    int idx = tid + j * 256;
    int d = idx >> 3, nn = (idx & 7) * 8;
    bf16x8 o;
#pragma unroll
    for (int jj = 0; jj < 8; ++jj) o[jj] = t[(nn + jj) * 72 + d];
    *(bf16x8*)(vt + (size_t)(h * 64 + d) * 2048 + n0 + nn) = o;
  }
}

// ---------------------------------------------------------------------------
// Flash attention, block-shared KV, UNIFORM <=8-tile CHUNKING.
// No-max exp2 softmax => partials over disjoint kt ranges merge by ADDITION.
// Grid 1280: bid -> h = bid&15, u = bid>>4 in [0,80):
//   u<32:  qt = 31 - (u>>2), c = u&3      (4 chunks, longest first)
//   u<56:  t = u-32; qt = 23 - t/3, c = t%3
//   u<72:  t = u-56; qt = 15 - (t>>1), c = t&1
//   else:  qt = 7 - (u-72), c = 0
// Chunk covers kt in [8c, min(8c+7, qt)] -> serial chain <= 8 tiles.
// qt<=7 (single chunk): normalize + write bf16 directly.
// Else: write unnormalized f32 O + lsum to scratch slot c; merge adds.
// ---------------------------------------------------------------------------
#define STAGE(BUF, KT)                                                         \
  {                                                                            \
    _Pragma("unroll")                                                          \
    for (int p = 0; p < 2; ++p) {                                              \
      int row = srow + p * 32;                                                 \
      int sch = sc ^ (row & 7);                                                \
      gload_lds16(Kg + (size_t)((KT) * 64 + row) * 1024 + h * 64 + sch * 8,    \
                  &Ks[BUF][w * 512 + p * 2048]);                               \
      gload_lds16(Vg + ((size_t)h * 64 + row) * 2048 + (KT) * 64 + sch * 8,    \
                  &Vs[BUF][w * 512 + p * 2048]);                               \
    }                                                                          \
  }

__global__ __launch_bounds__(256, 4) void attn_kernel(
    const __bf16* __restrict__ Qg, const __bf16* __restrict__ Kg,
    const __bf16* __restrict__ Vg, __bf16* __restrict__ Og,
    float* __restrict__ oS, float* __restrict__ lS)
{
  __shared__ __align__(16) __bf16 Ks[2][4096];
  __shared__ __align__(16) __bf16 Vs[2][4096];
  __shared__ __align__(16) __bf16 Ps[4][16 * 72];

  const int bid = blockIdx.x;
  const int h = bid & 15;
  const int u = bid >> 4;
  int qt, c;
  if (u < 32)      { qt = 31 - (u >> 2); c = u & 3; }
  else if (u < 56) { int t = u - 32; qt = 23 - t / 3; c = t % 3; }
  else if (u < 72) { int t = u - 56; qt = 15 - (t >> 1); c = t & 1; }
  else             { qt = 7 - (u - 72); c = 0; }
  const int kts = c * 8;
  const int kte = min(kts + 7, qt);
  const int q0 = qt * 64;

  const int tid = threadIdx.x, w = tid >> 6, l = tid & 63;
  const int g = l >> 4, c16 = l & 15;
  const int srow = tid >> 3;
  const int sc   = tid & 7;

  __bf16* Ps_w = &Ps[w][0];

  const __bf16* qbase = Qg + (size_t)(q0 + w * 16 + c16) * 1024 + h * 64 + g * 8;
  const bf16x8 qf0 = *(const bf16x8*)(qbase);
  const bf16x8 qf1 = *(const bf16x8*)(qbase + 32);

  f32x4 o[4] = {};
  float lsum[4] = {0.f, 0.f, 0.f, 0.f};

  STAGE(0, kts)

  for (int kt = kts; kt <= kte; ++kt) {
    const int cur = (kt - kts) & 1;
    __syncthreads();
    if (kt < kte) STAGE(cur ^ 1, kt + 1)

    const __bf16* Kb = Ks[cur];
    const __bf16* Vb = Vs[cur];

    f32x4 s[4] = {};
#pragma unroll
    for (int nt = 0; nt < 4; ++nt) {
      int r = nt * 16 + c16;
      bf16x8 k0 = *(const bf16x8*)((char*)Kb + r * 128 + ((g ^ (r & 7)) * 16));
      bf16x8 k1 = *(const bf16x8*)((char*)Kb + r * 128 + (((4 + g) ^ (r & 7)) * 16));
      s[nt] = __builtin_amdgcn_mfma_f32_16x16x32_bf16(qf0, k0, s[nt], 0, 0, 0);
      s[nt] = __builtin_amdgcn_mfma_f32_16x16x32_bf16(qf1, k1, s[nt], 0, 0, 0);
    }

    const bool diag = (kt == qt);       // only the true diagonal tile masks
#pragma unroll
    for (int r = 0; r < 4; ++r) {
#pragma unroll
      for (int nt = 0; nt < 4; ++nt) {
        float sv = s[nt][r];
        if (diag && (nt * 16 + c16) > (w * 16 + g * 4 + r)) sv = -1e30f;
        float e = exp2f(sv);
        Ps_w[(g * 4 + r) * 72 + nt * 16 + c16] = (__bf16)e;
        lsum[r] += e;
      }
    }

#pragma unroll
    for (int ks = 0; ks < 2; ++ks) {
      bf16x8 pa = *(const bf16x8*)((char*)Ps_w + c16 * 144 + ks * 64 + g * 16);
#pragma unroll
      for (int nt = 0; nt < 4; ++nt) {
        int r = nt * 16 + c16;
        bf16x8 vb = *(const bf16x8*)((char*)Vb + r * 128 + (((ks * 4 + g) ^ (r & 7)) * 16));
        o[nt] = __builtin_amdgcn_mfma_f32_16x16x32_bf16(pa, vb, o[nt], 0, 0, 0);
      }
    }
  }

  // row-sum reduce across the 16-lane group
#pragma unroll
  for (int m2 = 1; m2 < 16; m2 <<= 1) {
#pragma unroll
    for (int r = 0; r < 4; ++r) lsum[r] += __shfl_xor(lsum[r], m2, 16);
  }

  if (qt <= 7) {
    // single-chunk strip: normalize and store bf16
#pragma unroll
    for (int r = 0; r < 4; ++r) {
      float rinv = 1.0f / lsum[r];
      int qi = q0 + w * 16 + g * 4 + r;
#pragma unroll
      for (int nt = 0; nt < 4; ++nt)
        Og[(size_t)qi * 1024 + h * 64 + nt * 16 + c16] = (__bf16)(o[nt][r] * rinv);
    }
  } else {
    // store unnormalized f32 partial + lsum to scratch slot c
    float* oBase = oS + (size_t)c * 2048 * 1024;
#pragma unroll
    for (int r = 0; r < 4; ++r) {
      int row = q0 + w * 16 + g * 4 + r;
#pragma unroll
      for (int nt = 0; nt < 4; ++nt)
        oBase[(size_t)row * 1024 + h * 64 + nt * 16 + c16] = o[nt][r];
      if (c16 == 0)
        lS[(size_t)c * 2048 * 16 + (size_t)row * 16 + h] = lsum[r];
    }
  }
}

// ---------------------------------------------------------------------------
// merge: rows 512..2047 (qt >= 8): og = (sum_c oS[c]) / (sum_c lS[c]), bf16.
// nch = qt/8 + 1 in {2,3,4}. Grid 1536 (one block per row), 256 thr x 4 cols.
// ---------------------------------------------------------------------------
__global__ __launch_bounds__(256) void merge_chunks(
    const float* __restrict__ oS, const float* __restrict__ lS,
    __bf16* __restrict__ Og)
{
  int row = 512 + blockIdx.x;
  int col = threadIdx.x * 4;
  int h = col >> 6;
  int nch = (row >> 9) + 1;                 // (row>>6)/8 + 1 = row>>9 + 1
  float lsum = 0.f;
  f32x4 sum = {};
#pragma unroll 4
  for (int c = 0; c < nch; ++c) {
    lsum += lS[(size_t)c * 2048 * 16 + (size_t)row * 16 + h];
    sum += *(const f32x4*)(oS + (size_t)c * 2048 * 1024 + (size_t)row * 1024 + col);
  }
  float rinv = 1.0f / lsum;
  bf16x4 ob;
  ob[0] = (__bf16)(sum[0] * rinv); ob[1] = (__bf16)(sum[1] * rinv);
  ob[2] = (__bf16)(sum[2] * rinv); ob[3] = (__bf16)(sum[3] * rinv);
  *(bf16x4*)(Og + (size_t)row * 1024 + col) = ob;
}

// ---------------------------------------------------------------------------
extern "C" void kernel_launch(void* const* d_in, const int* in_sizes, int n_in,
                              void* d_out, int out_size, void* d_ws, size_t ws_size,
                              hipStream_t stream) {
  const float* x   = (const float*)d_in[0];
  const float* Wq  = (const float*)d_in[1];
  const float* Wk  = (const float*)d_in[2];
  const float* Wv  = (const float*)d_in[3];
  const float* Wo  = (const float*)d_in[4];
  const float* sqk = (const float*)d_in[5];
  float* out = (float*)d_out;

  __bf16* xb  = (__bf16*)d_ws;                  // [2048][1024]
  __bf16* wqb = xb  + (size_t)2048 * 1024;      // [1024][1024]
  __bf16* wkb = wqb + (size_t)1024 * 1024;
  __bf16* wvb = wkb + (size_t)1024 * 1024;
  __bf16* wob = wvb + (size_t)1024 * 1024;
  __bf16* q   = wob + (size_t)1024 * 1024;      // [2048][1024]
  __bf16* k   = q   + (size_t)2048 * 1024;
  __bf16* v   = k   + (size_t)2048 * 1024;
  __bf16* qn  = v   + (size_t)2048 * 1024;
  __bf16* kn  = qn  + (size_t)2048 * 1024;
  __bf16* vtb = kn  + (size_t)2048 * 1024;      // [16][64][2048]
  __bf16* og  = vtb + (size_t)2048 * 1024;      // [2048][1024]
  float*  oS  = (float*)(og + (size_t)2048 * 1024);  // [4][2048][1024] f32 = 32 MB
  float*  lS  = oS + (size_t)4 * 2048 * 1024;        // [4][2048][16]  f32

  convert_all<<<3072, 256, 0, stream>>>(x, Wq, Wk, Wv, Wo, xb);
  gemm_bt<64, 128, __bf16><<<dim3(8, 32, 3), 256, 0, stream>>>(
      xb, wqb, wkb, wvb, q, k, v, 2048, 1024, 1024);
  rope_norm<<<4096, 256, 0, stream>>>(q, k, sqk, qn, kn);
  vtrans<<<dim3(32, 16), 256, 0, stream>>>(v, vtb);
  attn_kernel<<<1280, 256, 0, stream>>>(qn, kn, vtb, og, oS, lS);
  merge_chunks<<<1536, 256, 0, stream>>>(oS, lS, og);
  gemm_bt<64, 64, float><<<dim3(16, 32, 1), 256, 0, stream>>>(
      og, wob, wob, wob, out, out, out, 2048, 1024, 1024);
}

// Round 11
// 77.381 us; speedup vs baseline: 1.0992x; 1.0992x over previous
//
#include <hip/hip_runtime.h>
#include <hip/hip_bf16.h>

typedef float f32x4 __attribute__((ext_vector_type(4)));
typedef __bf16 bf16x8 __attribute__((ext_vector_type(8)));
typedef __bf16 bf16x4 __attribute__((ext_vector_type(4)));

__device__ __forceinline__ void gload_lds16(const __bf16* g, __bf16* l) {
  __builtin_amdgcn_global_load_lds(
      (const __attribute__((address_space(1))) void*)g,
      (__attribute__((address_space(3))) void*)l, 16, 0, 0);
}

// ---------------------------------------------------------------------------
// convert: fp32 -> bf16 for x (2M elems) and Wq/Wk/Wv/Wo (1M each)
// ---------------------------------------------------------------------------
__global__ __launch_bounds__(256) void convert_all(
    const float* __restrict__ x, const float* __restrict__ wq,
    const float* __restrict__ wk, const float* __restrict__ wv,
    const float* __restrict__ wo, __bf16* __restrict__ dst)
{
  int t = blockIdx.x * 256 + threadIdx.x;
  const float* src; size_t soff;
  if (t < 262144) { src = x; soff = (size_t)t * 8; }
  else {
    int r = (t - 262144) >> 17;
    src = (r == 0) ? wq : (r == 1) ? wk : (r == 2) ? wv : wo;
    soff = (size_t)((t - 262144) & 131071) * 8;
  }
  float4 f0 = *(const float4*)(src + soff);
  float4 f1 = *(const float4*)(src + soff + 4);
  bf16x8 o;
  o[0]=(__bf16)f0.x; o[1]=(__bf16)f0.y; o[2]=(__bf16)f0.z; o[3]=(__bf16)f0.w;
  o[4]=(__bf16)f1.x; o[5]=(__bf16)f1.y; o[6]=(__bf16)f1.z; o[7]=(__bf16)f1.w;
  *(bf16x8*)(dst + (size_t)t * 8) = o;
}

// ---------------------------------------------------------------------------
// GEMM: C[m][n] = sum_k A[m][k] * B[n][k].  Templated tile BMxBN, BK=64.
// global_load_lds w=16, swizzle on the global source (rule #21).
// ROPE=true (QKV path, BN=128): z<2 epilogue applies RoPE + justnorm + sqk
// scale in fp32 registers before the bf16 store -- head h=bn*2+wc lives
// entirely in one wave quadrant (4 frags x 16 lanes = 64 cols).
// ---------------------------------------------------------------------------
template <int BM, int BN, typename OutT, bool ROPE>
__global__ __launch_bounds__(256) void gemm_bt(
    const __bf16* __restrict__ A,
    const __bf16* __restrict__ B0, const __bf16* __restrict__ B1, const __bf16* __restrict__ B2,
    OutT* __restrict__ C0, OutT* __restrict__ C1, OutT* __restrict__ C2,
    int M, int N, int K, const float* __restrict__ sqkp)
{
  const __bf16* B = (blockIdx.z == 0) ? B0 : (blockIdx.z == 1) ? B1 : B2;
  OutT* C = (blockIdx.z == 0) ? C0 : (blockIdx.z == 1) ? C1 : C2;

  constexpr int BK = 64;
  constexpr int MT = BM / 32, NT = BN / 32;
  __shared__ __align__(16) __bf16 As[BM * BK];
  __shared__ __align__(16) __bf16 Bs[BN * BK];

  const int tid = threadIdx.x, w = tid >> 6, l = tid & 63;
  const int wr = w >> 1, wc = w & 1;
  const int g = l >> 4, c16 = l & 15;
  const int bm = blockIdx.y, bn = blockIdx.x;
  const int sr8 = l >> 3, sc = l & 7;

  f32x4 acc[MT][NT] = {};
  const int nk = K >> 6;

  for (int kt = 0; kt < nk; ++kt) {
    __syncthreads();
#pragma unroll
    for (int i = w; i < BM / 8; i += 4) {
      int row = i * 8 + sr8;
      int sch = sc ^ (row & 7);
      gload_lds16(A + (size_t)(bm * BM + row) * K + kt * 64 + sch * 8, As + i * 8 * 64);
    }
#pragma unroll
    for (int i = w; i < BN / 8; i += 4) {
      int row = i * 8 + sr8;
      int sch = sc ^ (row & 7);
      gload_lds16(B + (size_t)(bn * BN + row) * K + kt * 64 + sch * 8, Bs + i * 8 * 64);
    }
    __syncthreads();

    bf16x8 af[MT][2], bf[NT][2];
#pragma unroll
    for (int mt = 0; mt < MT; ++mt) {
      int row = wr * (BM / 2) + mt * 16 + c16;
#pragma unroll
      for (int kk = 0; kk < 2; ++kk)
        af[mt][kk] = *(const bf16x8*)(As + row * 64 + (((kk * 4 + g) ^ (row & 7)) * 8));
    }
#pragma unroll
    for (int nt = 0; nt < NT; ++nt) {
      int row = wc * (BN / 2) + nt * 16 + c16;
#pragma unroll
      for (int kk = 0; kk < 2; ++kk)
        bf[nt][kk] = *(const bf16x8*)(Bs + row * 64 + (((kk * 4 + g) ^ (row & 7)) * 8));
    }
#pragma unroll
    for (int kk = 0; kk < 2; ++kk)
#pragma unroll
      for (int mt = 0; mt < MT; ++mt)
#pragma unroll
        for (int nt = 0; nt < NT; ++nt)
          acc[mt][nt] = __builtin_amdgcn_mfma_f32_16x16x32_bf16(af[mt][kk], bf[nt][kk], acc[mt][nt], 0, 0, 0);
  }

  bool done = false;
  if constexpr (ROPE) {
    static_assert(!ROPE || NT == 4, "ROPE epilogue assumes BN=128 (one head per quadrant)");
    if (blockIdx.z < 2) {
      const bool isQ = (blockIdx.z == 0);
      const int hcol = bn * BN + wc * (BN / 2);          // head base col
      float sq[4];
#pragma unroll
      for (int nt = 0; nt < 4; ++nt) sq[nt] = sqkp[hcol + nt * 16 + c16] * 32.0f;
      const float QSC = 8.0f * 1.4426950408889634f;      // sqrt(64)*log2(e)
      const float L = 0.415241011860919f;                // log2(10000)/32
      const float inv0 = exp2f(-(float)c16 * L);
      const float inv1 = exp2f(-(float)(c16 + 16) * L);
#pragma unroll
      for (int mt = 0; mt < MT; ++mt) {
#pragma unroll
        for (int r = 0; r < 4; ++r) {
          int row = bm * BM + wr * (BM / 2) + mt * 16 + g * 4 + r;
          float s0, c0, s1, c1;
          sincosf((float)row * inv0, &s0, &c0);
          sincosf((float)row * inv1, &s1, &c1);
          float v0 = acc[mt][0][r], v1 = acc[mt][1][r];
          float v2 = acc[mt][2][r], v3 = acc[mt][3][r];
          float n0 = v0 * c0 - v2 * s0;                  // col i = c16
          float n2 = v0 * s0 + v2 * c0;                  // col i+32
          float n1 = v1 * c1 - v3 * s1;                  // col i = c16+16
          float n3 = v1 * s1 + v3 * c1;                  // col i+48
          float ss = n0 * n0 + n1 * n1 + n2 * n2 + n3 * n3;
#pragma unroll
          for (int m2 = 1; m2 < 16; m2 <<= 1) ss += __shfl_xor(ss, m2, 16);
          float rinv = rsqrtf(ss);
          if (isQ) rinv *= QSC;
          C[(size_t)row * N + hcol +  0 + c16] = (OutT)(n0 * sq[0] * rinv);
          C[(size_t)row * N + hcol + 16 + c16] = (OutT)(n1 * sq[1] * rinv);
          C[(size_t)row * N + hcol + 32 + c16] = (OutT)(n2 * sq[2] * rinv);
          C[(size_t)row * N + hcol + 48 + c16] = (OutT)(n3 * sq[3] * rinv);
        }
      }
      done = true;
    }
  }
  if (!done) {
#pragma unroll
    for (int mt = 0; mt < MT; ++mt)
#pragma unroll
      for (int nt = 0; nt < NT; ++nt)
#pragma unroll
        for (int r = 0; r < 4; ++r) {
          int row = bm * BM + wr * (BM / 2) + mt * 16 + g * 4 + r;
          int col = bn * BN + wc * (BN / 2) + nt * 16 + c16;
          C[(size_t)row * N + col] = (OutT)acc[mt][nt][r];
        }
  }
}

// ---------------------------------------------------------------------------
// V transpose: vt[h][d][n] = v[n][h*64+d]
// ---------------------------------------------------------------------------
__global__ __launch_bounds__(256) void vtrans(const __bf16* __restrict__ v, __bf16* __restrict__ vt)
{
  __shared__ __align__(16) __bf16 t[64 * 72];
  int h = blockIdx.y;
  int n0 = blockIdx.x * 64;
  int tid = threadIdx.x;
#pragma unroll
  for (int j = 0; j < 2; ++j) {
    int idx = tid + j * 256;
    int r = idx >> 3, c = (idx & 7) * 8;
    bf16x8 val = *(const bf16x8*)(v + (size_t)(n0 + r) * 1024 + h * 64 + c);
    *(bf16x8*)&t[r * 72 + c] = val;
  }
  __syncthreads();
#pragma unroll
  for (int j = 0; j < 2; ++j) {
    int idx = tid + j * 256;
    int d = idx >> 3, nn = (idx & 7) * 8;
    bf16x8 o;
#pragma unroll
    for (int jj = 0; jj < 8; ++jj) o[jj] = t[(nn + jj) * 72 + d];
    *(bf16x8*)(vt + (size_t)(h * 64 + d) * 2048 + n0 + nn) = o;
  }
}

// ---------------------------------------------------------------------------
// Flash attention, block-shared KV, 2-way KV-SPLIT for long strips (round-9
// structure: measured equal to 8-tile chunking with half the merge traffic).
// Grid 768:
//   b in [0,512): split strips. p=b>>5 -> qt=16+p; half=(b>>4)&1; h=b&15.
//   b in [512,768): unsplit strips qt=15-((b-512)>>4), h=b&15.
// ---------------------------------------------------------------------------
#define STAGE(BUF, KT)                                                         \
  {                                                                            \
    _Pragma("unroll")                                                          \
    for (int p = 0; p < 2; ++p) {                                              \
      int row = srow + p * 32;                                                 \
      int sch = sc ^ (row & 7);                                                \
      gload_lds16(Kg + (size_t)((KT) * 64 + row) * 1024 + h * 64 + sch * 8,    \
                  &Ks[BUF][w * 512 + p * 2048]);                               \
      gload_lds16(Vg + ((size_t)h * 64 + row) * 2048 + (KT) * 64 + sch * 8,    \
                  &Vs[BUF][w * 512 + p * 2048]);                               \
    }                                                                          \
  }

__global__ __launch_bounds__(256, 4) void attn_kernel(
    const __bf16* __restrict__ Qg, const __bf16* __restrict__ Kg,
    const __bf16* __restrict__ Vg, __bf16* __restrict__ Og,
    float* __restrict__ oS, float* __restrict__ lS)
{
  __shared__ __align__(16) __bf16 Ks[2][4096];
  __shared__ __align__(16) __bf16 Vs[2][4096];
  __shared__ __align__(16) __bf16 Ps[4][16 * 72];

  const int b = blockIdx.x;
  int h, qt, kts, kte, sidx;
  if (b < 512) {
    int p = b >> 5;
    qt = 16 + p;
    sidx = (b >> 4) & 1;
    h = b & 15;
    int mid = (qt + 1) >> 1;
    kts = sidx ? mid : 0;
    kte = sidx ? qt : (mid - 1);
  } else {
    qt = 15 - ((b - 512) >> 4);
    h = b & 15;
    kts = 0; kte = qt; sidx = -1;
  }
  const int q0 = qt * 64;

  const int tid = threadIdx.x, w = tid >> 6, l = tid & 63;
  const int g = l >> 4, c16 = l & 15;
  const int srow = tid >> 3;
  const int sc   = tid & 7;

  __bf16* Ps_w = &Ps[w][0];

  const __bf16* qbase = Qg + (size_t)(q0 + w * 16 + c16) * 1024 + h * 64 + g * 8;
  const bf16x8 qf0 = *(const bf16x8*)(qbase);
  const bf16x8 qf1 = *(const bf16x8*)(qbase + 32);

  f32x4 o[4] = {};
  float lsum[4] = {0.f, 0.f, 0.f, 0.f};

  STAGE(0, kts)

  for (int kt = kts; kt <= kte; ++kt) {
    const int cur = (kt - kts) & 1;
    __syncthreads();
    if (kt < kte) STAGE(cur ^ 1, kt + 1)

    const __bf16* Kb = Ks[cur];
    const __bf16* Vb = Vs[cur];

    f32x4 s[4] = {};
#pragma unroll
    for (int nt = 0; nt < 4; ++nt) {
      int r = nt * 16 + c16;
      bf16x8 k0 = *(const bf16x8*)((char*)Kb + r * 128 + ((g ^ (r & 7)) * 16));
      bf16x8 k1 = *(const bf16x8*)((char*)Kb + r * 128 + (((4 + g) ^ (r & 7)) * 16));
      s[nt] = __builtin_amdgcn_mfma_f32_16x16x32_bf16(qf0, k0, s[nt], 0, 0, 0);
      s[nt] = __builtin_amdgcn_mfma_f32_16x16x32_bf16(qf1, k1, s[nt], 0, 0, 0);
    }

    const bool diag = (kt == qt);
#pragma unroll
    for (int r = 0; r < 4; ++r) {
#pragma unroll
      for (int nt = 0; nt < 4; ++nt) {
        float sv = s[nt][r];
        if (diag && (nt * 16 + c16) > (w * 16 + g * 4 + r)) sv = -1e30f;
        float e = exp2f(sv);
        Ps_w[(g * 4 + r) * 72 + nt * 16 + c16] = (__bf16)e;
        lsum[r] += e;
      }
    }

#pragma unroll
    for (int ks = 0; ks < 2; ++ks) {
      bf16x8 pa = *(const bf16x8*)((char*)Ps_w + c16 * 144 + ks * 64 + g * 16);
#pragma unroll
      for (int nt = 0; nt < 4; ++nt) {
        int r = nt * 16 + c16;
        bf16x8 vb = *(const bf16x8*)((char*)Vb + r * 128 + (((ks * 4 + g) ^ (r & 7)) * 16));
        o[nt] = __builtin_amdgcn_mfma_f32_16x16x32_bf16(pa, vb, o[nt], 0, 0, 0);
      }
    }
  }

#pragma unroll
  for (int m2 = 1; m2 < 16; m2 <<= 1) {
#pragma unroll
    for (int r = 0; r < 4; ++r) lsum[r] += __shfl_xor(lsum[r], m2, 16);
  }

  if (sidx < 0) {
#pragma unroll
    for (int r = 0; r < 4; ++r) {
      float rinv = 1.0f / lsum[r];
      int qi = q0 + w * 16 + g * 4 + r;
#pragma unroll
      for (int nt = 0; nt < 4; ++nt)
        Og[(size_t)qi * 1024 + h * 64 + nt * 16 + c16] = (__bf16)(o[nt][r] * rinv);
    }
  } else {
    float* oBase = oS + (size_t)sidx * 1024 * 1024;
#pragma unroll
    for (int r = 0; r < 4; ++r) {
      int row = q0 + w * 16 + g * 4 + r - 1024;
#pragma unroll
      for (int nt = 0; nt < 4; ++nt)
        oBase[(size_t)row * 1024 + h * 64 + nt * 16 + c16] = o[nt][r];
      if (c16 == 0)
        lS[(size_t)sidx * 1024 * 16 + (size_t)row * 16 + h] = lsum[r];
    }
  }
}

// ---------------------------------------------------------------------------
// merge: rows 1024..2047: og = (oA + oB) / (lA + lB), bf16.
// ---------------------------------------------------------------------------
__global__ __launch_bounds__(256) void merge_halves(
    const float* __restrict__ oS, const float* __restrict__ lS,
    __bf16* __restrict__ Og)
{
  int row = blockIdx.x;
  int col = threadIdx.x * 4;
  int h = col >> 6;
  float lsum = lS[(size_t)row * 16 + h] + lS[(size_t)(1024 + row) * 16 + h];
  float rinv = 1.0f / lsum;
  f32x4 a = *(const f32x4*)(oS + (size_t)row * 1024 + col);
  f32x4 bb = *(const f32x4*)(oS + (size_t)(1024 * 1024) + (size_t)row * 1024 + col);
  f32x4 sum = a + bb;
  bf16x4 ob;
  ob[0] = (__bf16)(sum[0] * rinv); ob[1] = (__bf16)(sum[1] * rinv);
  ob[2] = (__bf16)(sum[2] * rinv); ob[3] = (__bf16)(sum[3] * rinv);
  *(bf16x4*)(Og + (size_t)(1024 + row) * 1024 + col) = ob;
}

// ---------------------------------------------------------------------------
extern "C" void kernel_launch(void* const* d_in, const int* in_sizes, int n_in,
                              void* d_out, int out_size, void* d_ws, size_t ws_size,
                              hipStream_t stream) {
  const float* x   = (const float*)d_in[0];
  const float* Wq  = (const float*)d_in[1];
  const float* Wk  = (const float*)d_in[2];
  const float* Wv  = (const float*)d_in[3];
  const float* Wo  = (const float*)d_in[4];
  const float* sqk = (const float*)d_in[5];
  float* out = (float*)d_out;

  __bf16* xb  = (__bf16*)d_ws;                  // [2048][1024]
  __bf16* wqb = xb  + (size_t)2048 * 1024;      // [1024][1024]
  __bf16* wkb = wqb + (size_t)1024 * 1024;
  __bf16* wvb = wkb + (size_t)1024 * 1024;
  __bf16* wob = wvb + (size_t)1024 * 1024;
  __bf16* qn  = wob + (size_t)1024 * 1024;      // [2048][1024] rope+norm'd q
  __bf16* kn  = qn  + (size_t)2048 * 1024;      // [2048][1024] rope+norm'd k
  __bf16* v   = kn  + (size_t)2048 * 1024;      // [2048][1024]
  __bf16* vtb = v   + (size_t)2048 * 1024;      // [16][64][2048]
  __bf16* og  = vtb + (size_t)2048 * 1024;      // [2048][1024]
  float*  oS  = (float*)(og + (size_t)2048 * 1024);  // [2][1024][1024] f32
  float*  lS  = oS + (size_t)2 * 1024 * 1024;        // [2][1024][16]  f32

  convert_all<<<3072, 256, 0, stream>>>(x, Wq, Wk, Wv, Wo, xb);
  gemm_bt<64, 128, __bf16, true><<<dim3(8, 32, 3), 256, 0, stream>>>(
      xb, wqb, wkb, wvb, qn, kn, v, 2048, 1024, 1024, sqk);
  vtrans<<<dim3(32, 16), 256, 0, stream>>>(v, vtb);
  attn_kernel<<<768, 256, 0, stream>>>(qn, kn, vtb, og, oS, lS);
  merge_halves<<<1024, 256, 0, stream>>>(oS, lS, og);
  gemm_bt<64, 64, float, false><<<dim3(16, 32, 1), 256, 0, stream>>>(
      og, wob, wob, wob, out, out, out, 2048, 1024, 1024, nullptr);
}

// Round 12
// 77.218 us; speedup vs baseline: 1.1015x; 1.0021x over previous
//
#include <hip/hip_runtime.h>
#include <hip/hip_bf16.h>

typedef float f32x4 __attribute__((ext_vector_type(4)));
typedef __bf16 bf16x8 __attribute__((ext_vector_type(8)));
typedef __bf16 bf16x4 __attribute__((ext_vector_type(4)));

__device__ __forceinline__ void gload_lds16(const __bf16* g, __bf16* l) {
  __builtin_amdgcn_global_load_lds(
      (const __attribute__((address_space(1))) void*)g,
      (__attribute__((address_space(3))) void*)l, 16, 0, 0);
}

// ---------------------------------------------------------------------------
// convert: fp32 -> bf16 for x (2M elems) and Wq/Wk/Wv/Wo (1M each)
// ---------------------------------------------------------------------------
__global__ __launch_bounds__(256) void convert_all(
    const float* __restrict__ x, const float* __restrict__ wq,
    const float* __restrict__ wk, const float* __restrict__ wv,
    const float* __restrict__ wo, __bf16* __restrict__ dst)
{
  int t = blockIdx.x * 256 + threadIdx.x;
  const float* src; size_t soff;
  if (t < 262144) { src = x; soff = (size_t)t * 8; }
  else {
    int r = (t - 262144) >> 17;
    src = (r == 0) ? wq : (r == 1) ? wk : (r == 2) ? wv : wo;
    soff = (size_t)((t - 262144) & 131071) * 8;
  }
  float4 f0 = *(const float4*)(src + soff);
  float4 f1 = *(const float4*)(src + soff + 4);
  bf16x8 o;
  o[0]=(__bf16)f0.x; o[1]=(__bf16)f0.y; o[2]=(__bf16)f0.z; o[3]=(__bf16)f0.w;
  o[4]=(__bf16)f1.x; o[5]=(__bf16)f1.y; o[6]=(__bf16)f1.z; o[7]=(__bf16)f1.w;
  *(bf16x8*)(dst + (size_t)t * 8) = o;
}

// ---------------------------------------------------------------------------
// GEMM: C[m][n] = sum_k A[m][k] * B[n][k].  Tile BM x BN, BK in {64,128}.
// global_load_lds w=16, swizzle chunk lc^(row&7) on the global source;
// reads use slot (kk*4+g)^(row&7) (rule #21 both-sides).
// kk-blocked fragment reads keep VGPR pressure low at BK=128.
// ROPE=true (QKV, BN=128): z<2 epilogue = RoPE + justnorm + sqk in fp32.
// ---------------------------------------------------------------------------
template <int BM, int BN, int BK, typename OutT, bool ROPE>
__global__ __launch_bounds__(256) void gemm_bt(
    const __bf16* __restrict__ A,
    const __bf16* __restrict__ B0, const __bf16* __restrict__ B1, const __bf16* __restrict__ B2,
    OutT* __restrict__ C0, OutT* __restrict__ C1, OutT* __restrict__ C2,
    int M, int N, int K, const float* __restrict__ sqkp)
{
  const __bf16* B = (blockIdx.z == 0) ? B0 : (blockIdx.z == 1) ? B1 : B2;
  OutT* C = (blockIdx.z == 0) ? C0 : (blockIdx.z == 1) ? C1 : C2;

  constexpr int MT = BM / 32, NT = BN / 32, KK = BK / 32;
  constexpr int CPR = BK / 8;          // 16B chunks per row
  constexpr int RPI = 64 / CPR;        // rows per gload inst
  __shared__ __align__(16) __bf16 As[BM * BK];
  __shared__ __align__(16) __bf16 Bs[BN * BK];

  const int tid = threadIdx.x, w = tid >> 6, l = tid & 63;
  const int wr = w >> 1, wc = w & 1;
  const int g = l >> 4, c16 = l & 15;
  const int bm = blockIdx.y, bn = blockIdx.x;
  const int lr = l / CPR, lc = l % CPR;

  f32x4 acc[MT][NT] = {};
  const int nk = K / BK;

  for (int kt = 0; kt < nk; ++kt) {
    __syncthreads();
#pragma unroll
    for (int i = w; i < BM / RPI; i += 4) {
      int row = i * RPI + lr;
      int sch = lc ^ (row & 7);
      gload_lds16(A + (size_t)(bm * BM + row) * K + kt * BK + sch * 8, As + i * RPI * BK);
    }
#pragma unroll
    for (int i = w; i < BN / RPI; i += 4) {
      int row = i * RPI + lr;
      int sch = lc ^ (row & 7);
      gload_lds16(B + (size_t)(bn * BN + row) * K + kt * BK + sch * 8, Bs + i * RPI * BK);
    }
    __syncthreads();

#pragma unroll
    for (int kk = 0; kk < KK; ++kk) {
      bf16x8 af[MT], bf[NT];
#pragma unroll
      for (int mt = 0; mt < MT; ++mt) {
        int row = wr * (BM / 2) + mt * 16 + c16;
        af[mt] = *(const bf16x8*)(As + row * BK + (((kk * 4 + g) ^ (row & 7)) * 8));
      }
#pragma unroll
      for (int nt = 0; nt < NT; ++nt) {
        int row = wc * (BN / 2) + nt * 16 + c16;
        bf[nt] = *(const bf16x8*)(Bs + row * BK + (((kk * 4 + g) ^ (row & 7)) * 8));
      }
#pragma unroll
      for (int mt = 0; mt < MT; ++mt)
#pragma unroll
        for (int nt = 0; nt < NT; ++nt)
          acc[mt][nt] = __builtin_amdgcn_mfma_f32_16x16x32_bf16(af[mt], bf[nt], acc[mt][nt], 0, 0, 0);
    }
  }

  bool done = false;
  if constexpr (ROPE) {
    static_assert(!ROPE || NT == 4, "ROPE epilogue assumes BN=128");
    if (blockIdx.z < 2) {
      const bool isQ = (blockIdx.z == 0);
      const int hcol = bn * BN + wc * (BN / 2);
      float sq[4];
#pragma unroll
      for (int nt = 0; nt < 4; ++nt) sq[nt] = sqkp[hcol + nt * 16 + c16] * 32.0f;
      const float QSC = 8.0f * 1.4426950408889634f;      // sqrt(64)*log2(e)
      const float L = 0.415241011860919f;                // log2(10000)/32
      const float inv0 = exp2f(-(float)c16 * L);
      const float inv1 = exp2f(-(float)(c16 + 16) * L);
#pragma unroll
      for (int mt = 0; mt < MT; ++mt) {
#pragma unroll
        for (int r = 0; r < 4; ++r) {
          int row = bm * BM + wr * (BM / 2) + mt * 16 + g * 4 + r;
          float s0, c0, s1, c1;
          sincosf((float)row * inv0, &s0, &c0);
          sincosf((float)row * inv1, &s1, &c1);
          float v0 = acc[mt][0][r], v1 = acc[mt][1][r];
          float v2 = acc[mt][2][r], v3 = acc[mt][3][r];
          float n0 = v0 * c0 - v2 * s0;
          float n2 = v0 * s0 + v2 * c0;
          float n1 = v1 * c1 - v3 * s1;
          float n3 = v1 * s1 + v3 * c1;
          float ss = n0 * n0 + n1 * n1 + n2 * n2 + n3 * n3;
#pragma unroll
          for (int m2 = 1; m2 < 16; m2 <<= 1) ss += __shfl_xor(ss, m2, 16);
          float rinv = rsqrtf(ss);
          if (isQ) rinv *= QSC;
          C[(size_t)row * N + hcol +  0 + c16] = (OutT)(n0 * sq[0] * rinv);
          C[(size_t)row * N + hcol + 16 + c16] = (OutT)(n1 * sq[1] * rinv);
          C[(size_t)row * N + hcol + 32 + c16] = (OutT)(n2 * sq[2] * rinv);
          C[(size_t)row * N + hcol + 48 + c16] = (OutT)(n3 * sq[3] * rinv);
        }
      }
      done = true;
    }
  }
  if (!done) {
#pragma unroll
    for (int mt = 0; mt < MT; ++mt)
#pragma unroll
      for (int nt = 0; nt < NT; ++nt)
#pragma unroll
        for (int r = 0; r < 4; ++r) {
          int row = bm * BM + wr * (BM / 2) + mt * 16 + g * 4 + r;
          int col = bn * BN + wc * (BN / 2) + nt * 16 + c16;
          C[(size_t)row * N + col] = (OutT)acc[mt][nt][r];
        }
  }
}

// ---------------------------------------------------------------------------
// V transpose: vt[h][d][n] = v[n][h*64+d]
// ---------------------------------------------------------------------------
__global__ __launch_bounds__(256) void vtrans(const __bf16* __restrict__ v, __bf16* __restrict__ vt)
{
  __shared__ __align__(16) __bf16 t[64 * 72];
  int h = blockIdx.y;
  int n0 = blockIdx.x * 64;
  int tid = threadIdx.x;
#pragma unroll
  for (int j = 0; j < 2; ++j) {
    int idx = tid + j * 256;
    int r = idx >> 3, c = (idx & 7) * 8;
    bf16x8 val = *(const bf16x8*)(v + (size_t)(n0 + r) * 1024 + h * 64 + c);
    *(bf16x8*)&t[r * 72 + c] = val;
  }
  __syncthreads();
#pragma unroll
  for (int j = 0; j < 2; ++j) {
    int idx = tid + j * 256;
    int d = idx >> 3, nn = (idx & 7) * 8;
    bf16x8 o;
#pragma unroll
    for (int jj = 0; jj < 8; ++jj) o[jj] = t[(nn + jj) * 72 + d];
    *(bf16x8*)(vt + (size_t)(h * 64 + d) * 2048 + n0 + nn) = o;
  }
}

// ---------------------------------------------------------------------------
// Flash attention, block-shared KV, 2-way KV-SPLIT (round-9 balance).
// SWAPPED QK^T: S^T = mfma(K, Q) -> thread (g,c16) holds P for q-row c16,
// kv cols kjb*16+g*4+(0..3) = 4 CONTIGUOUS elems -> 4 ds_write_b64 replace
// 16 ds_write_b16 (LDS pipe was the throughput floor). PV & pa unchanged.
// lsum: per-thread over 16 vals + 2 shuffles; redistributed via 16-float LDS.
// ---------------------------------------------------------------------------
#define STAGE(BUF, KT)                                                         \
  {                                                                            \
    _Pragma("unroll")                                                          \
    for (int p = 0; p < 2; ++p) {                                              \
      int row = srow + p * 32;                                                 \
      int sch = sc ^ (row & 7);                                                \
      gload_lds16(Kg + (size_t)((KT) * 64 + row) * 1024 + h * 64 + sch * 8,    \
                  &Ks[BUF][w * 512 + p * 2048]);                               \
      gload_lds16(Vg + ((size_t)h * 64 + row) * 2048 + (KT) * 64 + sch * 8,    \
                  &Vs[BUF][w * 512 + p * 2048]);                               \
    }                                                                          \
  }

__global__ __launch_bounds__(256, 4) void attn_kernel(
    const __bf16* __restrict__ Qg, const __bf16* __restrict__ Kg,
    const __bf16* __restrict__ Vg, __bf16* __restrict__ Og,
    float* __restrict__ oS, float* __restrict__ lS)
{
  __shared__ __align__(16) __bf16 Ks[2][4096];
  __shared__ __align__(16) __bf16 Vs[2][4096];
  __shared__ __align__(16) __bf16 Ps[4][16 * 72];

  const int b = blockIdx.x;
  int h, qt, kts, kte, sidx;
  if (b < 512) {
    int p = b >> 5;
    qt = 16 + p;
    sidx = (b >> 4) & 1;
    h = b & 15;
    int mid = (qt + 1) >> 1;
    kts = sidx ? mid : 0;
    kte = sidx ? qt : (mid - 1);
  } else {
    qt = 15 - ((b - 512) >> 4);
    h = b & 15;
    kts = 0; kte = qt; sidx = -1;
  }
  const int q0 = qt * 64;

  const int tid = threadIdx.x, w = tid >> 6, l = tid & 63;
  const int g = l >> 4, c16 = l & 15;
  const int srow = tid >> 3;
  const int sc   = tid & 7;

  __bf16* Ps_w = &Ps[w][0];
  const int qig = q0 + w * 16 + c16;         // this thread's q-row (global)

  const __bf16* qbase = Qg + (size_t)qig * 1024 + h * 64 + g * 8;
  const bf16x8 qf0 = *(const bf16x8*)(qbase);
  const bf16x8 qf1 = *(const bf16x8*)(qbase + 32);

  f32x4 o[4] = {};
  float lsum = 0.f;

  STAGE(0, kts)

  for (int kt = kts; kt <= kte; ++kt) {
    const int cur = (kt - kts) & 1;
    __syncthreads();
    if (kt < kte) STAGE(cur ^ 1, kt + 1)

    const __bf16* Kb = Ks[cur];
    const __bf16* Vb = Vs[cur];

    // S^T = K Q^T : s[kjb][r] = S[qi=c16][kj = kjb*16 + g*4 + r]
    f32x4 s[4] = {};
#pragma unroll
    for (int kjb = 0; kjb < 4; ++kjb) {
      int r = kjb * 16 + c16;
      bf16x8 k0 = *(const bf16x8*)((char*)Kb + r * 128 + ((g ^ (r & 7)) * 16));
      bf16x8 k1 = *(const bf16x8*)((char*)Kb + r * 128 + (((4 + g) ^ (r & 7)) * 16));
      s[kjb] = __builtin_amdgcn_mfma_f32_16x16x32_bf16(k0, qf0, s[kjb], 0, 0, 0);
      s[kjb] = __builtin_amdgcn_mfma_f32_16x16x32_bf16(k1, qf1, s[kjb], 0, 0, 0);
    }

    // P = exp2(S): 4 contiguous bf16 per (kjb) -> packed b64 writes
    const bool diag = (kt == qt);
#pragma unroll
    for (int kjb = 0; kjb < 4; ++kjb) {
      bf16x4 pk;
#pragma unroll
      for (int r = 0; r < 4; ++r) {
        float sv = s[kjb][r];
        int kvg = kt * 64 + kjb * 16 + g * 4 + r;
        if (diag && kvg > qig) sv = -1e30f;
        float e = exp2f(sv);
        pk[r] = (__bf16)e;
        lsum += e;
      }
      *(bf16x4*)((char*)Ps_w + c16 * 144 + kjb * 32 + g * 8) = pk;
    }

    // O += P V  (unchanged: pa rows c16, V^T rows d)
#pragma unroll
    for (int ks = 0; ks < 2; ++ks) {
      bf16x8 pa = *(const bf16x8*)((char*)Ps_w + c16 * 144 + ks * 64 + g * 16);
#pragma unroll
      for (int nt = 0; nt < 4; ++nt) {
        int r = nt * 16 + c16;
        bf16x8 vb = *(const bf16x8*)((char*)Vb + r * 128 + (((ks * 4 + g) ^ (r & 7)) * 16));
        o[nt] = __builtin_amdgcn_mfma_f32_16x16x32_bf16(pa, vb, o[nt], 0, 0, 0);
      }
    }
  }

  // reduce lsum over the 4 g-lanes sharing q-row c16
  lsum += __shfl_xor(lsum, 16);
  lsum += __shfl_xor(lsum, 32);

  if (sidx < 0) {
    // redistribute row sums: lane g==0 publishes row c16; all read rows g*4+r
    float* lsh = (float*)Ps_w;
    if (g == 0) lsh[c16] = lsum;
    __builtin_amdgcn_s_waitcnt(0);           // lgkmcnt(0): publish before read
#pragma unroll
    for (int r = 0; r < 4; ++r) {
      float rinv = 1.0f / lsh[g * 4 + r];
      int qi = q0 + w * 16 + g * 4 + r;
#pragma unroll
      for (int nt = 0; nt < 4; ++nt)
        Og[(size_t)qi * 1024 + h * 64 + nt * 16 + c16] = (__bf16)(o[nt][r] * rinv);
    }
  } else {
    float* oBase = oS + (size_t)sidx * 1024 * 1024;
#pragma unroll
    for (int r = 0; r < 4; ++r) {
      int row = q0 + w * 16 + g * 4 + r - 1024;
#pragma unroll
      for (int nt = 0; nt < 4; ++nt)
        oBase[(size_t)row * 1024 + h * 64 + nt * 16 + c16] = o[nt][r];
    }
    if (g == 0)
      lS[(size_t)sidx * 1024 * 16 + (size_t)(qig - 1024) * 16 + h] = lsum;
  }
}

// ---------------------------------------------------------------------------
// merge: rows 1024..2047: og = (oA + oB) / (lA + lB), bf16.
// ---------------------------------------------------------------------------
__global__ __launch_bounds__(256) void merge_halves(
    const float* __restrict__ oS, const float* __restrict__ lS,
    __bf16* __restrict__ Og)
{
  int row = blockIdx.x;
  int col = threadIdx.x * 4;
  int h = col >> 6;
  float lsum = lS[(size_t)row * 16 + h] + lS[(size_t)(1024 + row) * 16 + h];
  float rinv = 1.0f / lsum;
  f32x4 a = *(const f32x4*)(oS + (size_t)row * 1024 + col);
  f32x4 bb = *(const f32x4*)(oS + (size_t)(1024 * 1024) + (size_t)row * 1024 + col);
  f32x4 sum = a + bb;
  bf16x4 ob;
  ob[0] = (__bf16)(sum[0] * rinv); ob[1] = (__bf16)(sum[1] * rinv);
  ob[2] = (__bf16)(sum[2] * rinv); ob[3] = (__bf16)(sum[3] * rinv);
  *(bf16x4*)(Og + (size_t)(1024 + row) * 1024 + col) = ob;
}

// ---------------------------------------------------------------------------
extern "C" void kernel_launch(void* const* d_in, const int* in_sizes, int n_in,
                              void* d_out, int out_size, void* d_ws, size_t ws_size,
                              hipStream_t stream) {
  const float* x   = (const float*)d_in[0];
  const float* Wq  = (const float*)d_in[1];
  const float* Wk  = (const float*)d_in[2];
  const float* Wv  = (const float*)d_in[3];
  const float* Wo  = (const float*)d_in[4];
  const float* sqk = (const float*)d_in[5];
  float* out = (float*)d_out;

  __bf16* xb  = (__bf16*)d_ws;                  // [2048][1024]
  __bf16* wqb = xb  + (size_t)2048 * 1024;      // [1024][1024]
  __bf16* wkb = wqb + (size_t)1024 * 1024;
  __bf16* wvb = wkb + (size_t)1024 * 1024;
  __bf16* wob = wvb + (size_t)1024 * 1024;
  __bf16* qn  = wob + (size_t)1024 * 1024;      // [2048][1024] rope+norm'd q
  __bf16* kn  = qn  + (size_t)2048 * 1024;      // [2048][1024] rope+norm'd k
  __bf16* v   = kn  + (size_t)2048 * 1024;      // [2048][1024]
  __bf16* vtb = v   + (size_t)2048 * 1024;      // [16][64][2048]
  __bf16* og  = vtb + (size_t)2048 * 1024;      // [2048][1024]
  float*  oS  = (float*)(og + (size_t)2048 * 1024);  // [2][1024][1024] f32
  float*  lS  = oS + (size_t)2 * 1024 * 1024;        // [2][1024][16]  f32

  convert_all<<<3072, 256, 0, stream>>>(x, Wq, Wk, Wv, Wo, xb);
  gemm_bt<64, 128, 128, __bf16, true><<<dim3(8, 32, 3), 256, 0, stream>>>(
      xb, wqb, wkb, wvb, qn, kn, v, 2048, 1024, 1024, sqk);
  vtrans<<<dim3(32, 16), 256, 0, stream>>>(v, vtb);
  attn_kernel<<<768, 256, 0, stream>>>(qn, kn, vtb, og, oS, lS);
  merge_halves<<<1024, 256, 0, stream>>>(oS, lS, og);
  gemm_bt<64, 64, 128, float, false><<<dim3(16, 32, 1), 256, 0, stream>>>(
      og, wob, wob, wob, out, out, out, 2048, 1024, 1024, nullptr);
}